// Round 5
// baseline (810.996 us; speedup 1.0000x reference)
//
#include <hip/hip_runtime.h>

typedef unsigned short u16;
typedef unsigned long long u64;
typedef float f32x4 __attribute__((ext_vector_type(4)));
typedef short bf16x8 __attribute__((ext_vector_type(8)));

#define XB 102400      // Cin*T*V per batch
#define TV 1600
#define OB 204800      // Cout*T*V per batch

// ws float offsets
#define WS_PAPK_H 0        // PA B-frags hi: [3h][2ih][64l][8e] = 3072 u16
#define WS_PAPK_L 1536
#define WS_WY_H   3072     // Wy A-frags: [6kt][8Mt][64l][8e] = 24576 u16
#define WS_WY_L   15360
#define WS_WR_H   27648    // Wr A-frags: [2kt][8Mt][64l][8e] = 8192 u16
#define WS_WR_L   31744
#define WS_BIASY  35840    // [128][25] f32
#define WS_C0     39040    // [128][25] f32
#define WS_AFF    42240    // [128][2] = (ay, ar)
#define WS_PART   42496    // [64 slots][512] f32
#define WS_YR     75264    // bf16 y|r buffer: [16384 m][y 128*25 | r 128*25] u16

#define MFMA(a, b, c) __builtin_amdgcn_mfma_f32_16x16x32_bf16(a, b, c, 0, 0, 0)

__device__ __forceinline__ u16 f2bf(float x) {
    unsigned u = __float_as_uint(x);
    return (u16)((u + 0x7fffu + ((u >> 16) & 1u)) >> 16);
}
__device__ __forceinline__ float bf2f(u16 h) {
    return __uint_as_float(((unsigned)h) << 16);
}
__device__ __forceinline__ void split2(float x, u16& h, u16& l) {
    h = f2bf(x);
    float hf = bf2f(h);
    l = f2bf(x - hf);
}

__global__ void prep(const float* __restrict__ PA, const float* __restrict__ Wv,
                     const float* __restrict__ bv, const float* __restrict__ Wr,
                     float* __restrict__ ws)
{
    int tid = blockIdx.x * blockDim.x + threadIdx.x;
    int nthr = gridDim.x * blockDim.x;
    u16* PH = (u16*)(ws + WS_PAPK_H);
    u16* PL = (u16*)(ws + WS_PAPK_L);
    for (int idx = tid; idx < 3072; idx += nthr) {
        int e = idx & 7, l = (idx >> 3) & 63, ihw = (idx >> 9) & 1, h = idx >> 10;
        int i = ihw * 16 + (l & 15), j = ((l >> 4) << 3) + e;
        float v = (i < 25 && j < 25) ? PA[(h * 25 + i) * 25 + j] : 0.f;
        u16 hh, ll; split2(v, hh, ll);
        PH[idx] = hh; PL[idx] = ll;
    }
    u16* YH = (u16*)(ws + WS_WY_H);
    u16* YL = (u16*)(ws + WS_WY_L);
    for (int idx = tid; idx < 24576; idx += nthr) {
        int e = idx & 7, l = (idx >> 3) & 63, Mt = (idx >> 9) & 7, kt = idx >> 12;
        int hc = kt * 32 + ((l >> 4) << 3) + e;
        int h = hc >> 6, c = hc & 63, o = Mt * 16 + (l & 15);
        float v = Wv[(h * 128 + o) * 64 + c];
        u16 hh, ll; split2(v, hh, ll);
        YH[idx] = hh; YL[idx] = ll;
    }
    u16* RH = (u16*)(ws + WS_WR_H);
    u16* RL = (u16*)(ws + WS_WR_L);
    for (int idx = tid; idx < 8192; idx += nthr) {
        int e = idx & 7, l = (idx >> 3) & 63, Mt = (idx >> 9) & 7, kt = idx >> 12;
        int c = kt * 32 + ((l >> 4) << 3) + e;
        int o = Mt * 16 + (l & 15);
        float v = Wr[o * 64 + c];
        u16 hh, ll; split2(v, hh, ll);
        RH[idx] = hh; RL[idx] = ll;
    }
    for (int f = tid; f < 128 * 25; f += nthr) {
        int o = f / 25, i = f % 25;
        float s = 0.f;
        for (int h = 0; h < 3; ++h) {
            float rs = 0.f;
            for (int j = 0; j < 25; ++j) rs += PA[(h * 25 + i) * 25 + j];
            s = fmaf(bv[h * 128 + o], rs, s);
        }
        ws[WS_BIASY + f] = s;
    }
    for (int f = tid; f < 64 * 512; f += nthr) ws[WS_PART + f] = 0.f;
}

// One WG per 4 m (m = b*64+t), 512 threads = 8 waves.
// z[k'][i] per mi: k' 0..191 = xa (3 heads), 192..255 = x (identity head).
// y[o] = sum_{k'<192} Wy z ; r[o] = sum_{k'>=192} Wr z. bf16 y|r -> ws.
__global__ __launch_bounds__(512, 4) void gsa_compute(
    const float* __restrict__ x, const float* __restrict__ br,
    float* __restrict__ ws)
{
    __shared__ __align__(16) u16 xs_h[8192], xs_l[8192];   // [64 c][4mi*32 j] swizzled
    __shared__ __align__(16) u16 z_h[8192], z_l[8192];     // [32 i][256 k'] swizzled
    __shared__ __align__(16) u16 tile[6400];               // [y 128*25 | r 128*25]

    const int tid = threadIdx.x;
    const int wg  = blockIdx.x;
    const int m0  = wg * 4;
    const int b   = m0 >> 6, t0 = m0 & 63;
    const int lane = tid & 63, w = tid >> 6;
    const int g = lane >> 4, l15 = lane & 15;
    const int ctw = w >> 1, ihw = w & 1;

    // ---- stage x -> xs (bf16 hi/lo, XOR-swizzled) ----
    const float* xb = x + b * XB + t0 * 25;
    for (int idx = tid; idx < 1600; idx += 512) {
        int c = idx / 25, q = idx - c * 25;
        f32x4 v = *(const f32x4*)(xb + c * TV + q * 4);
        #pragma unroll
        for (int u = 0; u < 4; ++u) {
            int jl = q * 4 + u;                 // 0..99
            int mi = jl / 25, j = jl - mi * 25;
            u16 hh, ll; split2(v[u], hh, ll);
            int byt = (c << 8) + ((mi * 32 + j) << 1);
            byt ^= (c & 7) << 4;
            *(u16*)((char*)xs_h + byt) = hh;
            *(u16*)((char*)xs_l + byt) = ll;
        }
    }
    // zero j-pads 25..31
    for (int idx = tid; idx < 1792; idx += 512) {
        int c = idx / 28, rem = idx - c * 28;
        int mi = rem / 7, j = 25 + (rem - mi * 7);
        int byt = (c << 8) + ((mi * 32 + j) << 1);
        byt ^= (c & 7) << 4;
        *(u16*)((char*)xs_h + byt) = 0;
        *(u16*)((char*)xs_l + byt) = 0;
    }

    // ---- persistent fragments ----
    const bf16x8* WYH = (const bf16x8*)(ws + WS_WY_H);
    const bf16x8* WYL = (const bf16x8*)(ws + WS_WY_L);
    const bf16x8* WRH = (const bf16x8*)(ws + WS_WR_H);
    const bf16x8* WRL = (const bf16x8*)(ws + WS_WR_L);
    const bf16x8* PAH = (const bf16x8*)(ws + WS_PAPK_H);
    const bf16x8* PAL = (const bf16x8*)(ws + WS_PAPK_L);

    bf16x8 wy_h[6];
    #pragma unroll
    for (int kt = 0; kt < 6; ++kt) wy_h[kt] = WYH[(kt * 8 + w) * 64 + lane];
    bf16x8 wr_hf[2];
    #pragma unroll
    for (int kt = 0; kt < 2; ++kt) wr_hf[kt] = WRH[(kt * 8 + w) * 64 + lane];
    bf16x8 pa_hf[3], pa_lf[3];
    #pragma unroll
    for (int h = 0; h < 3; ++h) {
        pa_hf[h] = PAH[(h * 2 + ihw) * 64 + lane];
        pa_lf[h] = PAL[(h * 2 + ihw) * 64 + lane];
    }
    bf16x8 iden;
    #pragma unroll
    for (int e = 0; e < 8; ++e)
        iden[e] = (short)(((g * 8 + e) == (ihw * 16 + l15)) ? 0x3F80 : 0);

    float byv[2][4], brv[4];
    #pragma unroll
    for (int ih = 0; ih < 2; ++ih) {
        int i = ih * 16 + l15; int ii = i < 25 ? i : 24;
        #pragma unroll
        for (int r_ = 0; r_ < 4; ++r_)
            byv[ih][r_] = ws[WS_BIASY + (w * 16 + g * 4 + r_) * 25 + ii];
    }
    #pragma unroll
    for (int r_ = 0; r_ < 4; ++r_) brv[r_] = br[w * 16 + g * 4 + r_];

    float psy[4] = {0,0,0,0}, pssy[4] = {0,0,0,0};
    float psr[4] = {0,0,0,0}, pssr[4] = {0,0,0,0};

    u16* ybr = (u16*)(ws + WS_YR);

    auto gemm0 = [&](int mi) {
        int arow = ctw * 16 + l15;
        int abyt = ((arow << 8) + ((mi * 32 + g * 8) << 1)) ^ ((arow & 7) << 4);
        bf16x8 a_h = *(const bf16x8*)((char*)xs_h + abyt);
        bf16x8 a_l = *(const bf16x8*)((char*)xs_l + abyt);
        int i = ihw * 16 + l15;
        int zrow = i << 9;                 // i * 256 u16 * 2B
        int zx = (i & 7) << 4;
        #pragma unroll
        for (int h = 0; h < 3; ++h) {
            f32x4 d = {0.f, 0.f, 0.f, 0.f};
            d = MFMA(a_h, pa_hf[h], d);
            d = MFMA(a_l, pa_hf[h], d);
            d = MFMA(a_h, pa_lf[h], d);
            u64 hb = 0, lb = 0;
            #pragma unroll
            for (int r_ = 0; r_ < 4; ++r_) {
                u16 hh, ll; split2(d[r_], hh, ll);
                hb |= ((u64)hh) << (16 * r_);
                lb |= ((u64)ll) << (16 * r_);
            }
            int byt = (zrow + ((h * 64 + ctw * 16 + g * 4) << 1)) ^ zx;
            *(u64*)((char*)z_h + byt) = hb;
            *(u64*)((char*)z_l + byt) = lb;
        }
        {   // identity head -> k' 192..255
            f32x4 d = {0.f, 0.f, 0.f, 0.f};
            d = MFMA(a_h, iden, d);
            d = MFMA(a_l, iden, d);
            u64 hb = 0, lb = 0;
            #pragma unroll
            for (int r_ = 0; r_ < 4; ++r_) {
                u16 hh, ll; split2(d[r_], hh, ll);
                hb |= ((u64)hh) << (16 * r_);
                lb |= ((u64)ll) << (16 * r_);
            }
            int byt = (zrow + ((192 + ctw * 16 + g * 4) << 1)) ^ zx;
            *(u64*)((char*)z_h + byt) = hb;
            *(u64*)((char*)z_l + byt) = lb;
        }
    };

    __syncthreads();
    gemm0(0);

    for (int mi = 0; mi < 4; ++mi) {
        __syncthreads();           // z(mi) ready; coop-store(mi-1) done
        #pragma unroll
        for (int ih = 0; ih < 2; ++ih) {
            const int i = ih * 16 + l15;
            const int zrow = i << 9;
            const int zx = (i & 7) << 4;
            f32x4 accy = {0.f, 0.f, 0.f, 0.f};
            #pragma unroll
            for (int kt = 0; kt < 6; ++kt) {
                int byt = (zrow + ((kt * 32 + g * 8) << 1)) ^ zx;
                bf16x8 b_h = *(const bf16x8*)((char*)z_h + byt);
                bf16x8 b_l = *(const bf16x8*)((char*)z_l + byt);
                bf16x8 wl = WYL[(kt * 8 + w) * 64 + lane];
                accy = MFMA(wy_h[kt], b_h, accy);
                accy = MFMA(wy_h[kt], b_l, accy);
                accy = MFMA(wl, b_h, accy);
            }
            f32x4 accr = {0.f, 0.f, 0.f, 0.f};
            #pragma unroll
            for (int kt = 0; kt < 2; ++kt) {
                int byt = (zrow + (((6 + kt) * 32 + g * 8) << 1)) ^ zx;
                bf16x8 b_h = *(const bf16x8*)((char*)z_h + byt);
                bf16x8 b_l = *(const bf16x8*)((char*)z_l + byt);
                bf16x8 wl = WRL[(kt * 8 + w) * 64 + lane];
                accr = MFMA(wr_hf[kt], b_h, accr);
                accr = MFMA(wr_hf[kt], b_l, accr);
                accr = MFMA(wl, b_h, accr);
            }
            if (i < 25) {
                #pragma unroll
                for (int r_ = 0; r_ < 4; ++r_) {
                    int o = w * 16 + g * 4 + r_;
                    float vy = accy[r_], vr = accr[r_];
                    float vyb = vy + byv[ih][r_];
                    float vrb = vr + brv[r_];
                    psy[r_] += vyb;  pssy[r_] = fmaf(vyb, vyb, pssy[r_]);
                    psr[r_] += vrb;  pssr[r_] = fmaf(vrb, vrb, pssr[r_]);
                    tile[o * 25 + i] = f2bf(vy);
                    tile[3200 + o * 25 + i] = f2bf(vr);
                }
            }
        }
        __syncthreads();           // tile ready; z reads done
        // coop-store tile -> ybr (contiguous 12.8KB per m; 800 x 16B)
        {
            size_t base = (size_t)(m0 + mi) * 6400;
            for (int idx = tid; idx < 800; idx += 512) {
                f32x4 v = *(const f32x4*)((char*)tile + idx * 16);
                *(f32x4*)(ybr + base + idx * 8) = v;
            }
        }
        if (mi < 3) gemm0(mi + 1);
    }

    // ---- stats flush ----
    #pragma unroll
    for (int r_ = 0; r_ < 4; ++r_) {
        float a = psy[r_], bq = pssy[r_], cq = psr[r_], dq = pssr[r_];
        #pragma unroll
        for (int mk = 1; mk < 16; mk <<= 1) {
            a += __shfl_xor(a, mk, 64);  bq += __shfl_xor(bq, mk, 64);
            cq += __shfl_xor(cq, mk, 64); dq += __shfl_xor(dq, mk, 64);
        }
        if (l15 == 0) {
            int o = w * 16 + g * 4 + r_;
            float* P = ws + WS_PART + (size_t)(wg & 63) * 512;
            atomicAdd(&P[o], a);        atomicAdd(&P[128 + o], bq);
            atomicAdd(&P[256 + o], cq); atomicAdd(&P[384 + o], dq);
        }
    }
}

__global__ void pass_b(const float* __restrict__ gamma, const float* __restrict__ beta,
                       const float* __restrict__ gamma_r, const float* __restrict__ beta_r,
                       const float* __restrict__ br, float* __restrict__ ws)
{
    __shared__ float sums[512];
    int tid = threadIdx.x;
    float s = 0.f;
    for (int k = 0; k < 64; ++k) s += ws[WS_PART + k * 512 + tid];
    sums[tid] = s;
    __syncthreads();
    if (tid < 128) {
        int o = tid;
        const float inv = 1.0f / 409600.0f;
        float my = sums[o] * inv;
        float vy = sums[128 + o] * inv - my * my;
        float ay = gamma[o] * rsqrtf(vy + 1e-5f);
        float by = beta[o] - ay * my;
        float mr = sums[256 + o] * inv;
        float vr = sums[384 + o] * inv - mr * mr;
        float ar = gamma_r[o] * rsqrtf(vr + 1e-5f);
        float brf = beta_r[o] - ar * mr;
        ws[WS_AFF + o * 2] = ay;
        ws[WS_AFF + o * 2 + 1] = ar;
        float cb = by + ar * br[o] + brf;
        for (int i = 0; i < 25; ++i)
            ws[WS_C0 + o * 25 + i] = fmaf(ay, ws[WS_BIASY + o * 25 + i], cb);
    }
}

// One WG per 4 m: stage bf16 y|r, apply BN affines + relu, coalesced fp32 out.
__global__ __launch_bounds__(256, 2) void finish(float* __restrict__ out,
                                                 const float* __restrict__ ws)
{
    __shared__ __align__(16) u16 tl[25600];      // 4 m x 6400
    __shared__ float c0s[3200];
    __shared__ float affs[256];

    const int tid = threadIdx.x;
    const int m0 = blockIdx.x * 4;
    const int b = m0 >> 6, t0 = m0 & 63;
    const u16* ybr = (const u16*)(ws + WS_YR);

    for (int idx = tid; idx < 3200; idx += 256) {
        f32x4 v = *(const f32x4*)(ybr + (size_t)m0 * 6400 + idx * 8);
        *(f32x4*)((char*)tl + idx * 16) = v;
    }
    for (int idx = tid; idx < 3200; idx += 256) c0s[idx] = ws[WS_C0 + idx];
    if (tid < 256) affs[tid] = ws[WS_AFF + tid];
    __syncthreads();

    for (int idx = tid; idx < 3200; idx += 256) {
        int o = idx / 25, p = idx - o * 25;
        float ay = affs[o * 2], ar = affs[o * 2 + 1];
        f32x4 res;
        #pragma unroll
        for (int u = 0; u < 4; ++u) {
            int ti = p * 4 + u;                // 0..99
            int mt = ti / 25, i = ti - mt * 25;
            float yv = bf2f(tl[mt * 6400 + o * 25 + i]);
            float rv = bf2f(tl[mt * 6400 + 3200 + o * 25 + i]);
            res[u] = fmaxf(0.f, fmaf(ay, yv, fmaf(ar, rv, c0s[o * 25 + i])));
        }
        *(f32x4*)(out + (size_t)b * OB + o * 1600 + t0 * 25 + p * 4) = res;
    }
}

extern "C" void kernel_launch(void* const* d_in, const int* in_sizes, int n_in,
                              void* d_out, int out_size, void* d_ws, size_t ws_size,
                              hipStream_t stream) {
    const float* x       = (const float*)d_in[0];
    const float* PA      = (const float*)d_in[1];
    const float* Wv      = (const float*)d_in[2];
    const float* bv      = (const float*)d_in[3];
    const float* gamma   = (const float*)d_in[4];
    const float* beta    = (const float*)d_in[5];
    const float* Wr      = (const float*)d_in[6];
    const float* br      = (const float*)d_in[7];
    const float* gamma_r = (const float*)d_in[8];
    const float* beta_r  = (const float*)d_in[9];
    float* out = (float*)d_out;
    float* ws  = (float*)d_ws;

    prep<<<64, 256, 0, stream>>>(PA, Wv, bv, Wr, ws);
    gsa_compute<<<4096, 512, 0, stream>>>(x, br, ws);
    pass_b<<<1, 512, 0, stream>>>(gamma, beta, gamma_r, beta_r, br, ws);
    finish<<<4096, 256, 0, stream>>>(out, ws);
}

// Round 6
// 509.966 us; speedup vs baseline: 1.5903x; 1.5903x over previous
//
#include <hip/hip_runtime.h>

typedef unsigned short u16;
typedef unsigned int u32;
typedef unsigned long long u64;
typedef float f32x4 __attribute__((ext_vector_type(4)));
typedef short bf16x8 __attribute__((ext_vector_type(8)));

#define XB 102400      // Cin*T*V per batch
#define TV 1600
#define OB 204800      // Cout*T*V per batch

// ws float offsets
#define WS_PAPK_H 0        // PA B-frags: [3h][2ih][64l][8e] = 3072 u16
#define WS_WY_H   3072     // Wy A-frags: [6kt][8Mt][64l][8e] = 24576 u16
#define WS_WR_H   15360    // Wr A-frags: [2kt][8Mt][64l][8e] = 8192 u16
#define WS_BIASY  35840    // [128][25] f32
#define WS_C0     39040    // [128][25] f32
#define WS_AFF    42240    // [128][2] = (ay, ar)
#define WS_PART   42496    // [64 slots][512] f32
#define WS_YR     75264    // u32-packed (y|r<<16) buffer: [16384 m][128 o][25 i]

#define MFMA(a, b, c) __builtin_amdgcn_mfma_f32_16x16x32_bf16(a, b, c, 0, 0, 0)

__device__ __forceinline__ u16 f2bf(float x) {
    unsigned u = __float_as_uint(x);
    return (u16)((u + 0x7fffu + ((u >> 16) & 1u)) >> 16);
}
__device__ __forceinline__ float bf2f(u16 h) {
    return __uint_as_float(((unsigned)h) << 16);
}

__global__ void prep(const float* __restrict__ PA, const float* __restrict__ Wv,
                     const float* __restrict__ bv, const float* __restrict__ Wr,
                     float* __restrict__ ws)
{
    int tid = blockIdx.x * blockDim.x + threadIdx.x;
    int nthr = gridDim.x * blockDim.x;
    u16* PH = (u16*)(ws + WS_PAPK_H);
    for (int idx = tid; idx < 3072; idx += nthr) {
        int e = idx & 7, l = (idx >> 3) & 63, ihw = (idx >> 9) & 1, h = idx >> 10;
        int i = ihw * 16 + (l & 15), j = ((l >> 4) << 3) + e;
        float v = (i < 25 && j < 25) ? PA[(h * 25 + i) * 25 + j] : 0.f;
        PH[idx] = f2bf(v);
    }
    u16* YH = (u16*)(ws + WS_WY_H);
    for (int idx = tid; idx < 24576; idx += nthr) {
        int e = idx & 7, l = (idx >> 3) & 63, Mt = (idx >> 9) & 7, kt = idx >> 12;
        int hc = kt * 32 + ((l >> 4) << 3) + e;
        int h = hc >> 6, c = hc & 63, o = Mt * 16 + (l & 15);
        YH[idx] = f2bf(Wv[(h * 128 + o) * 64 + c]);
    }
    u16* RH = (u16*)(ws + WS_WR_H);
    for (int idx = tid; idx < 8192; idx += nthr) {
        int e = idx & 7, l = (idx >> 3) & 63, Mt = (idx >> 9) & 7, kt = idx >> 12;
        int c = kt * 32 + ((l >> 4) << 3) + e;
        int o = Mt * 16 + (l & 15);
        RH[idx] = f2bf(Wr[o * 64 + c]);
    }
    for (int f = tid; f < 128 * 25; f += nthr) {
        int o = f / 25, i = f % 25;
        float s = 0.f;
        for (int h = 0; h < 3; ++h) {
            float rs = 0.f;
            for (int j = 0; j < 25; ++j) rs += PA[(h * 25 + i) * 25 + j];
            s = fmaf(bv[h * 128 + o], rs, s);
        }
        ws[WS_BIASY + f] = s;
    }
    for (int f = tid; f < 64 * 512; f += nthr) ws[WS_PART + f] = 0.f;
}

// One WG per 4 m (m = b*64+t), 512 threads = 8 waves. Single-bf16 MFMA path.
// z[k'][i] per mi: k' 0..191 = xa (3 heads), 192..255 = x (identity head).
// y[o] = Wy(k'<192) z ; r[o] = Wr(k'>=192) z. Raw (y,r) u32-packed bf16 -> ws.
__global__ __launch_bounds__(512, 4) void gsa_compute(
    const float* __restrict__ x, const float* __restrict__ br,
    float* __restrict__ ws)
{
    __shared__ __align__(16) u16 xs_h[8192];   // [64 c][4mi*32 j] swizzled
    __shared__ __align__(16) u16 z_h[8192];    // [32 i][256 k'] swizzled
    __shared__ __align__(16) u32 tile32[3200]; // [128 o][25 i] packed (y,r)

    const int tid = threadIdx.x;
    const int wg  = blockIdx.x;
    const int m0  = wg * 4;
    const int b   = m0 >> 6, t0 = m0 & 63;
    const int lane = tid & 63, w = tid >> 6;
    const int g = lane >> 4, l15 = lane & 15;
    const int ctw = w >> 1, ihw = w & 1;

    // ---- stage x -> xs (bf16, XOR-swizzled) ----
    const float* xb = x + b * XB + t0 * 25;
    for (int idx = tid; idx < 1600; idx += 512) {
        int c = idx / 25, q = idx - c * 25;
        f32x4 v = *(const f32x4*)(xb + c * TV + q * 4);
        #pragma unroll
        for (int u = 0; u < 4; ++u) {
            int jl = q * 4 + u;                 // 0..99
            int mi = jl / 25, j = jl - mi * 25;
            int byt = (c << 8) + ((mi * 32 + j) << 1);
            byt ^= (c & 7) << 4;
            *(u16*)((char*)xs_h + byt) = f2bf(v[u]);
        }
    }
    // zero j-pads 25..31
    for (int idx = tid; idx < 1792; idx += 512) {
        int c = idx / 28, rem = idx - c * 28;
        int mi = rem / 7, j = 25 + (rem - mi * 7);
        int byt = (c << 8) + ((mi * 32 + j) << 1);
        byt ^= (c & 7) << 4;
        *(u16*)((char*)xs_h + byt) = 0;
    }

    // ---- persistent fragments (single bf16) ----
    const bf16x8* WYH = (const bf16x8*)(ws + WS_WY_H);
    const bf16x8* WRH = (const bf16x8*)(ws + WS_WR_H);
    const bf16x8* PAH = (const bf16x8*)(ws + WS_PAPK_H);

    bf16x8 wy_h[6];
    #pragma unroll
    for (int kt = 0; kt < 6; ++kt) wy_h[kt] = WYH[(kt * 8 + w) * 64 + lane];
    bf16x8 wr_hf[2];
    #pragma unroll
    for (int kt = 0; kt < 2; ++kt) wr_hf[kt] = WRH[(kt * 8 + w) * 64 + lane];
    bf16x8 pa_hf[3];
    #pragma unroll
    for (int h = 0; h < 3; ++h) pa_hf[h] = PAH[(h * 2 + ihw) * 64 + lane];
    bf16x8 iden;
    #pragma unroll
    for (int e = 0; e < 8; ++e)
        iden[e] = (short)(((g * 8 + e) == (ihw * 16 + l15)) ? 0x3F80 : 0);

    float byv[2][4], brv[4];
    #pragma unroll
    for (int ih = 0; ih < 2; ++ih) {
        int i = ih * 16 + l15; int ii = i < 25 ? i : 24;
        #pragma unroll
        for (int r_ = 0; r_ < 4; ++r_)
            byv[ih][r_] = ws[WS_BIASY + (w * 16 + g * 4 + r_) * 25 + ii];
    }
    #pragma unroll
    for (int r_ = 0; r_ < 4; ++r_) brv[r_] = br[w * 16 + g * 4 + r_];

    float psy[4] = {0,0,0,0}, pssy[4] = {0,0,0,0};
    float psr[4] = {0,0,0,0}, pssr[4] = {0,0,0,0};

    u32* ybr = (u32*)(ws + WS_YR);

    auto gemm0 = [&](int mi) {
        int arow = ctw * 16 + l15;
        int abyt = ((arow << 8) + ((mi * 32 + g * 8) << 1)) ^ ((arow & 7) << 4);
        bf16x8 a_h = *(const bf16x8*)((char*)xs_h + abyt);
        int i = ihw * 16 + l15;
        int zrow = i << 9;                 // i * 256 u16 * 2B
        int zx = (i & 7) << 4;
        #pragma unroll
        for (int h = 0; h < 3; ++h) {
            f32x4 d = {0.f, 0.f, 0.f, 0.f};
            d = MFMA(a_h, pa_hf[h], d);
            u64 hb = 0;
            #pragma unroll
            for (int r_ = 0; r_ < 4; ++r_) hb |= ((u64)f2bf(d[r_])) << (16 * r_);
            int byt = (zrow + ((h * 64 + ctw * 16 + g * 4) << 1)) ^ zx;
            *(u64*)((char*)z_h + byt) = hb;
        }
        {   // identity head -> k' 192..255
            f32x4 d = {0.f, 0.f, 0.f, 0.f};
            d = MFMA(a_h, iden, d);
            u64 hb = 0;
            #pragma unroll
            for (int r_ = 0; r_ < 4; ++r_) hb |= ((u64)f2bf(d[r_])) << (16 * r_);
            int byt = (zrow + ((192 + ctw * 16 + g * 4) << 1)) ^ zx;
            *(u64*)((char*)z_h + byt) = hb;
        }
    };

    __syncthreads();
    gemm0(0);

    for (int mi = 0; mi < 4; ++mi) {
        __syncthreads();           // z(mi) ready; tile32 free
        #pragma unroll
        for (int ih = 0; ih < 2; ++ih) {
            const int i = ih * 16 + l15;
            const int zrow = i << 9;
            const int zx = (i & 7) << 4;
            f32x4 accy = {0.f, 0.f, 0.f, 0.f};
            #pragma unroll
            for (int kt = 0; kt < 6; ++kt) {
                int byt = (zrow + ((kt * 32 + g * 8) << 1)) ^ zx;
                bf16x8 b_h = *(const bf16x8*)((char*)z_h + byt);
                accy = MFMA(wy_h[kt], b_h, accy);
            }
            f32x4 accr = {0.f, 0.f, 0.f, 0.f};
            #pragma unroll
            for (int kt = 0; kt < 2; ++kt) {
                int byt = (zrow + (((6 + kt) * 32 + g * 8) << 1)) ^ zx;
                bf16x8 b_h = *(const bf16x8*)((char*)z_h + byt);
                accr = MFMA(wr_hf[kt], b_h, accr);
            }
            if (i < 25) {
                #pragma unroll
                for (int r_ = 0; r_ < 4; ++r_) {
                    int o = w * 16 + g * 4 + r_;
                    float vy = accy[r_], vr = accr[r_];
                    float vyb = vy + byv[ih][r_];
                    float vrb = vr + brv[r_];
                    psy[r_] += vyb;  pssy[r_] = fmaf(vyb, vyb, pssy[r_]);
                    psr[r_] += vrb;  pssr[r_] = fmaf(vrb, vrb, pssr[r_]);
                    tile32[o * 25 + i] = (u32)f2bf(vy) | ((u32)f2bf(vr) << 16);
                }
            }
        }
        __syncthreads();           // tile32 ready; z reads done
        // coop-store tile -> ybr (contiguous 12.8KB per m; 800 x 16B)
        {
            size_t base = (size_t)(m0 + mi) * 3200;
            for (int idx = tid; idx < 800; idx += 512) {
                f32x4 v = *(const f32x4*)((char*)tile32 + idx * 16);
                *(f32x4*)(ybr + base + idx * 4) = v;
            }
        }
        if (mi < 3) gemm0(mi + 1);
    }

    // ---- stats flush ----
    #pragma unroll
    for (int r_ = 0; r_ < 4; ++r_) {
        float a = psy[r_], bq = pssy[r_], cq = psr[r_], dq = pssr[r_];
        #pragma unroll
        for (int mk = 1; mk < 16; mk <<= 1) {
            a += __shfl_xor(a, mk, 64);  bq += __shfl_xor(bq, mk, 64);
            cq += __shfl_xor(cq, mk, 64); dq += __shfl_xor(dq, mk, 64);
        }
        if (l15 == 0) {
            int o = w * 16 + g * 4 + r_;
            float* P = ws + WS_PART + (size_t)(wg & 63) * 512;
            atomicAdd(&P[o], a);        atomicAdd(&P[128 + o], bq);
            atomicAdd(&P[256 + o], cq); atomicAdd(&P[384 + o], dq);
        }
    }
}

__global__ void pass_b(const float* __restrict__ gamma, const float* __restrict__ beta,
                       const float* __restrict__ gamma_r, const float* __restrict__ beta_r,
                       const float* __restrict__ br, float* __restrict__ ws)
{
    __shared__ float sums[512];
    int tid = threadIdx.x;
    float s = 0.f;
    for (int k = 0; k < 64; ++k) s += ws[WS_PART + k * 512 + tid];
    sums[tid] = s;
    __syncthreads();
    if (tid < 128) {
        int o = tid;
        const float inv = 1.0f / 409600.0f;
        float my = sums[o] * inv;
        float vy = sums[128 + o] * inv - my * my;
        float ay = gamma[o] * rsqrtf(vy + 1e-5f);
        float by = beta[o] - ay * my;
        float mr = sums[256 + o] * inv;
        float vr = sums[384 + o] * inv - mr * mr;
        float ar = gamma_r[o] * rsqrtf(vr + 1e-5f);
        float brf = beta_r[o] - ar * mr;
        ws[WS_AFF + o * 2] = ay;
        ws[WS_AFF + o * 2 + 1] = ar;
        float cb = by + ar * br[o] + brf;
        for (int i = 0; i < 25; ++i)
            ws[WS_C0 + o * 25 + i] = fmaf(ay, ws[WS_BIASY + o * 25 + i], cb);
    }
}

// One WG per 4 m: stage packed (y,r), apply BN affines + relu, coalesced fp32 out.
__global__ __launch_bounds__(256) void finish(float* __restrict__ out,
                                              const float* __restrict__ ws)
{
    __shared__ __align__(16) u32 tl32[12800];    // 4 m x [128 o][25 i]

    const int tid = threadIdx.x;
    const int m0 = blockIdx.x * 4;
    const int b = m0 >> 6, t0 = m0 & 63;
    const u32* ybr = (const u32*)(ws + WS_YR);
    const float* __restrict__ C0 = ws + WS_C0;
    const float* __restrict__ AF = ws + WS_AFF;

    for (int idx = tid; idx < 3200; idx += 256) {
        f32x4 v = *(const f32x4*)(ybr + (size_t)m0 * 3200 + idx * 4);
        *(f32x4*)(tl32 + idx * 4) = v;
    }
    __syncthreads();

    for (int idx = tid; idx < 3200; idx += 256) {
        int o = idx / 25, p = idx - o * 25;
        float ay = AF[o * 2], ar = AF[o * 2 + 1];
        f32x4 res;
        #pragma unroll
        for (int u = 0; u < 4; ++u) {
            int ti = p * 4 + u;                // 0..99
            int mt = ti / 25, i = ti - mt * 25;
            u32 v = tl32[mt * 3200 + o * 25 + i];
            float yv = bf2f((u16)(v & 0xFFFFu));
            float rv = bf2f((u16)(v >> 16));
            res[u] = fmaxf(0.f, fmaf(ay, yv, fmaf(ar, rv, C0[o * 25 + i])));
        }
        *(f32x4*)(out + (size_t)b * OB + o * 1600 + t0 * 25 + p * 4) = res;
    }
}

extern "C" void kernel_launch(void* const* d_in, const int* in_sizes, int n_in,
                              void* d_out, int out_size, void* d_ws, size_t ws_size,
                              hipStream_t stream) {
    const float* x       = (const float*)d_in[0];
    const float* PA      = (const float*)d_in[1];
    const float* Wv      = (const float*)d_in[2];
    const float* bv      = (const float*)d_in[3];
    const float* gamma   = (const float*)d_in[4];
    const float* beta    = (const float*)d_in[5];
    const float* Wr      = (const float*)d_in[6];
    const float* br      = (const float*)d_in[7];
    const float* gamma_r = (const float*)d_in[8];
    const float* beta_r  = (const float*)d_in[9];
    float* out = (float*)d_out;
    float* ws  = (float*)d_ws;

    prep<<<64, 256, 0, stream>>>(PA, Wv, bv, Wr, ws);
    gsa_compute<<<4096, 512, 0, stream>>>(x, br, ws);
    pass_b<<<1, 512, 0, stream>>>(gamma, beta, gamma_r, beta_r, br, ws);
    finish<<<4096, 256, 0, stream>>>(out, ws);
}